// Round 1
// baseline (71.102 us; speedup 1.0000x reference)
//
#include <hip/hip_runtime.h>
#include <hip/hip_bf16.h>

// Problem constants
#define B_    8
#define C_    128
#define L_    16384
#define K_    7
#define IC_   64
#define CK_   896
#define P_    5462      // (L+6-7)/3 + 1
#define TP_   62        // owned q-columns per tile
#define NP_   64        // computed h-columns per tile (2 halo)
#define NT_   89        // ceil(16387 / (3*TP)) tiles per batch
#define NPOS_ 196       // window positions per block: 3*63+7
#define LDW_  136       // winT row stride (bf16 elems), 272B = 16-aligned
#define LDH_  72        // hB row stride (bf16 elems), 144B = 16-aligned

using bf16x8 = __attribute__((ext_vector_type(8))) __bf16;
using bf16x4 = __attribute__((ext_vector_type(4))) __bf16;
using bf16x2 = __attribute__((ext_vector_type(2))) __bf16;
using f32x4  = __attribute__((ext_vector_type(4))) float;

// ws layout (bytes)
#define W1KB_OFF  0         // [7][64][128] bf16 : W1kb[k][o][c] = W1[o][7c+k]
#define W2RB_OFF  114688    // [3][128][3][64] bf16 : W2rb[r][c][t][o] = W2[7c+r+3t][o] (0 if k>6)
#define B2SUM_OFF 262144    // [3][128] f32 : sum_t b2[7c+r+3t]
#define B2TAB_OFF 263680    // [3][3][128] f32 : b2[7c+r+3t] (0 if k>6)

__global__ void prep_kernel(const float* __restrict__ W1, const float* __restrict__ W2,
                            const float* __restrict__ b2, __bf16* __restrict__ W1kb,
                            __bf16* __restrict__ W2rb, float* __restrict__ B2sum,
                            float* __restrict__ B2tab) {
    int idx = blockIdx.x * blockDim.x + threadIdx.x;
    int stride = gridDim.x * blockDim.x;
    for (int i = idx; i < 7 * 64 * 128; i += stride) {
        int k = i >> 13, o = (i >> 7) & 63, c = i & 127;
        W1kb[i] = (__bf16)W1[o * CK_ + c * 7 + k];
    }
    for (int i = idx; i < 3 * 128 * 3 * 64; i += stride) {
        int o = i & 63, t = (i >> 6) % 3, c = (i / 192) & 127, r = i / 24576;
        int kk = r + 3 * t;
        W2rb[i] = (kk <= 6) ? (__bf16)W2[(c * 7 + kk) * 64 + o] : (__bf16)0.0f;
    }
    for (int i = idx; i < 3 * 3 * 128; i += stride) {
        int c = i & 127, t = (i >> 7) % 3, r = i / 384;
        int kk = r + 3 * t;
        B2tab[i] = (kk <= 6) ? b2[c * 7 + kk] : 0.0f;
    }
    for (int i = idx; i < 3 * 128; i += stride) {
        int c = i & 127, r = i >> 7;
        float s = 0.0f;
        for (int t = 0; t < 3; ++t) { int kk = r + 3 * t; if (kk <= 6) s += b2[c * 7 + kk]; }
        B2sum[i] = s;
    }
}

__global__ __launch_bounds__(256, 2)
void fused_kernel(const float* __restrict__ x, const float* __restrict__ b1,
                  const __bf16* __restrict__ W1kb, const __bf16* __restrict__ W2rb,
                  const float* __restrict__ B2sum, const float* __restrict__ B2tab,
                  float* __restrict__ out) {
    __shared__ __align__(16) __bf16 winT[NPOS_][LDW_];  // winT[pos][c], transposed window
    __shared__ __align__(16) __bf16 hB[NP_][LDH_];      // hB[p_local][o]
    __shared__ float b1s[64];
    __shared__ float B2sumL[3][128];

    const int tid  = threadIdx.x;
    const int lane = tid & 63;
    const int w    = tid >> 6;      // wave 0..3
    const int row  = lane & 15;
    const int g    = lane >> 4;
    const int tile = blockIdx.x;
    const int b    = blockIdx.y;
    const int p0    = tile * TP_;
    const int pbase = p0 - 2;
    const int gx0   = 3 * pbase - 3;  // x-index of local pos 0 (before mod L)

    if (tid < 64) b1s[tid] = b1[tid];
    if (tid < 128) {
        #pragma unroll
        for (int r = 0; r < 3; ++r) B2sumL[r][tid] = B2sum[r * 128 + tid];
    }

    // ---- stage x window -> winT (bf16, transposed). wave handles 16 channel-pairs.
    const size_t xbase = ((size_t)b * C_) << 14;
    #pragma unroll
    for (int pp = 0; pp < 16; ++pp) {
        int c0 = (w * 16 + pp) * 2;
        const float* xr0 = x + xbase + ((size_t)c0 << 14);
        #pragma unroll
        for (int it = 0; it < 4; ++it) {
            int i = lane + (it << 6);
            if (i < NPOS_) {
                int xi = gx0 + i;
                xi += (xi < 0) ? L_ : 0;
                xi -= (xi >= L_) ? L_ : 0;
                float v0 = xr0[xi];
                float v1 = xr0[xi + L_];
                bf16x2 pk; pk[0] = (__bf16)v0; pk[1] = (__bf16)v1;
                *reinterpret_cast<bf16x2*>(&winT[i][c0]) = pk;
            }
        }
    }

    // ---- preload GEMM1 A-fragments (W1kb, L2-resident) : wave w owns o-tile w
    const bf16x8* W1v = reinterpret_cast<const bf16x8*>(W1kb);
    bf16x8 af1[28];
    #pragma unroll
    for (int k = 0; k < 7; ++k)
        #pragma unroll
        for (int cs = 0; cs < 4; ++cs)
            af1[k * 4 + cs] = W1v[(k * 64 + w * 16 + row) * 16 + cs * 4 + g];

    __syncthreads();

    // ---- GEMM1: h(64 x 64) = sum_k sum_c W1k[o][c] * winT[3p+k][c]
    f32x4 acc1[4];
    #pragma unroll
    for (int pt = 0; pt < 4; ++pt) acc1[pt] = (f32x4){0.f, 0.f, 0.f, 0.f};
    #pragma unroll
    for (int k = 0; k < 7; ++k) {
        #pragma unroll
        for (int cs = 0; cs < 4; ++cs) {
            bf16x8 a = af1[k * 4 + cs];
            #pragma unroll
            for (int pt = 0; pt < 4; ++pt) {
                const bf16x8 bfr = *reinterpret_cast<const bf16x8*>(
                    &winT[3 * (pt * 16 + row) + k][cs * 32 + g * 8]);
                acc1[pt] = __builtin_amdgcn_mfma_f32_16x16x32_bf16(a, bfr, acc1[pt], 0, 0, 0);
            }
        }
    }

    // ---- epilogue: +b1, relu, zero invalid halo columns, write hB (bf16)
    f32x4 b1v = *reinterpret_cast<const f32x4*>(&b1s[w * 16 + g * 4]);
    #pragma unroll
    for (int pt = 0; pt < 4; ++pt) {
        int pl = pt * 16 + row;
        int pg = pbase + pl;
        bool pvalid = ((unsigned)pg < (unsigned)P_);
        bf16x4 hq;
        #pragma unroll
        for (int i = 0; i < 4; ++i) {
            float v = acc1[pt][i] + b1v[i];
            v = fmaxf(v, 0.0f);
            hq[i] = pvalid ? (__bf16)v : (__bf16)0.0f;
        }
        *reinterpret_cast<bf16x4*>(&hB[pl][w * 16 + g * 4]) = hq;
    }

    // ---- preload GEMM2 A-fragments (W2rb): wave w owns c-tiles {2w, 2w+1}
    const bf16x8* W2v = reinterpret_cast<const bf16x8*>(W2rb);
    bf16x8 af2[2][14];
    #pragma unroll
    for (int cts = 0; cts < 2; ++cts) {
        int ct = w * 2 + cts;
        int idx = 0;
        #pragma unroll
        for (int r = 0; r < 3; ++r) {
            const int ntt = (r == 0) ? 3 : 2;
            #pragma unroll
            for (int t = 0; t < 3; ++t) {
                if (t < ntt) {
                    #pragma unroll
                    for (int os = 0; os < 2; ++os) {
                        af2[cts][idx] = W2v[((r * 128 + ct * 16 + row) * 3 + t) * 8 + os * 4 + g];
                        idx++;
                    }
                }
            }
        }
    }

    __syncthreads();

    // ---- GEMM2 + fold: out[c][3q+r-3] = sum_t sum_o W2rb[r][c][t][o] * h[o][q-t] + bias
    const bool edgeTile = (tile == 0) || (tile == NT_ - 1);
    for (int qt = 0; qt < 4; ++qt) {
        bf16x8 bq[3][2];
        #pragma unroll
        for (int t = 0; t < 3; ++t)
            #pragma unroll
            for (int os = 0; os < 2; ++os)
                bq[t][os] = *reinterpret_cast<const bf16x8*>(
                    &hB[qt * 16 + row + 2 - t][os * 32 + g * 8]);
        int q = p0 + qt * 16 + row;
        bool own = (qt * 16 + row) < TP_;
        #pragma unroll
        for (int cts = 0; cts < 2; ++cts) {
            int ct = w * 2 + cts;
            int c0 = ct * 16 + g * 4;
            int idx = 0;
            #pragma unroll
            for (int r = 0; r < 3; ++r) {
                f32x4 acc = (f32x4){0.f, 0.f, 0.f, 0.f};
                const int ntt = (r == 0) ? 3 : 2;
                #pragma unroll
                for (int t = 0; t < 3; ++t) {
                    if (t < ntt) {
                        #pragma unroll
                        for (int os = 0; os < 2; ++os) {
                            acc = __builtin_amdgcn_mfma_f32_16x16x32_bf16(
                                af2[cts][idx], bq[t][os], acc, 0, 0, 0);
                            idx++;
                        }
                    }
                }
                int pos = 3 * q + r;
                int lo  = pos - 3;
                f32x4 bias;
                if (!edgeTile) {
                    bias = *reinterpret_cast<const f32x4*>(&B2sumL[r][c0]);
                } else {
                    bias = (f32x4){0.f, 0.f, 0.f, 0.f};
                    #pragma unroll
                    for (int t = 0; t < 3; ++t) {
                        if (t < ntt && (unsigned)(q - t) < (unsigned)P_) {
                            #pragma unroll
                            for (int i = 0; i < 4; ++i)
                                bias[i] += B2tab[(r * 3 + t) * 128 + c0 + i];
                        }
                    }
                }
                if (own && (lo >= 0) && (lo < L_)) {
                    #pragma unroll
                    for (int i = 0; i < 4; ++i)
                        out[xbase + (((size_t)(c0 + i)) << 14) + lo] = acc[i] + bias[i];
                }
            }
        }
    }
}

extern "C" void kernel_launch(void* const* d_in, const int* in_sizes, int n_in,
                              void* d_out, int out_size, void* d_ws, size_t ws_size,
                              hipStream_t stream) {
    const float* x  = (const float*)d_in[0];
    const float* W1 = (const float*)d_in[1];
    const float* b1 = (const float*)d_in[2];
    const float* W2 = (const float*)d_in[3];
    const float* b2 = (const float*)d_in[4];
    float* out = (float*)d_out;
    char* ws = (char*)d_ws;
    __bf16* W1kb = (__bf16*)(ws + W1KB_OFF);
    __bf16* W2rb = (__bf16*)(ws + W2RB_OFF);
    float* B2sum = (float*)(ws + B2SUM_OFF);
    float* B2tab = (float*)(ws + B2TAB_OFF);

    prep_kernel<<<64, 256, 0, stream>>>(W1, W2, b2, W1kb, W2rb, B2sum, B2tab);
    fused_kernel<<<dim3(NT_, B_), 256, 0, stream>>>(x, b1, W1kb, W2rb, B2sum, B2tab, out);
}